// Round 1
// 209.000 us; speedup vs baseline: 1.1889x; 1.1889x over previous
//
#include <hip/hip_runtime.h>
#include <hip/hip_bf16.h>

// Problem constants (reference: B=2, S=2048, D=1024, H=16, HD=64)
#define BB 2
#define SS 2048
#define DD 1024
#define HH 16
#define HD 64
#define MM (BB * SS)   // 4096 rows in all GEMMs
#define NQKV 3072      // fused QKV output columns

// Wire formats (rounds 0-6 evidence): inputs fp32, pad_mask int32, OUTPUT fp32.
// MFMA fragment layouts validated bitwise vs VALU oracle (r5 == r3/r4).
typedef __attribute__((ext_vector_type(8))) short short8;   // 8 x bf16 frag
typedef __attribute__((ext_vector_type(4))) short s16x4;    // (short4 is a HIP builtin)
typedef __attribute__((ext_vector_type(4))) float floatx4;  // MFMA C/D frag
typedef __attribute__((ext_vector_type(4))) float f32x4;
using bf16 = __hip_bfloat16;

__device__ __forceinline__ float b2f(bf16 x) { return __bfloat162float(x); }
__device__ __forceinline__ short f2bs(float x) {
    bf16 h = __float2bfloat16(x);
    return *reinterpret_cast<short*>(&h);
}
__device__ __forceinline__ float bs2f(short s) {
    bf16 h; *reinterpret_cast<short*>(&h) = s; return __bfloat162float(h);
}

// LDS tiles addressed in 16B chunks (8 shorts), XOR swizzle (chunk ^ (row&7)).
__device__ __forceinline__ int lds_off(int row, int chunk) {
    return row * 64 + ((chunk ^ (row & 7)) * 8);
}

// Direct global->LDS async copy, 16B per lane. LDS dest is wave-uniform base
// + lane*16 (linear); the XOR swizzle is applied on the GLOBAL source address
// instead (linear-dest + pre-swizzled-src + swizzled-read pattern).
#define GL16(gp, lp)                                                        \
    __builtin_amdgcn_global_load_lds(                                       \
        (const __attribute__((address_space(1))) void*)(gp),                \
        (__attribute__((address_space(3))) void*)(lp), 16, 0, 0)

// ---------------------------------------------------------------------------
// Weight converters (unchanged).
// ---------------------------------------------------------------------------
__global__ __launch_bounds__(256) void convert_wcat(
    const float* __restrict__ Wq, const float* __restrict__ Wk,
    const float* __restrict__ Wv, short* __restrict__ dst)
{
    const int stride = gridDim.x * blockDim.x;
    for (int i = blockIdx.x * blockDim.x + threadIdx.x; i < NQKV * DD / 4; i += stride) {
        const int elem = i * 4;
        const int z    = elem >> 20;
        const int off  = elem & 0xFFFFF;
        const float* src = (z == 0) ? Wq : (z == 1) ? Wk : Wv;
        f32x4 v = *(const f32x4*)(src + off);
        s16x4 o; o[0] = f2bs(v[0]); o[1] = f2bs(v[1]); o[2] = f2bs(v[2]); o[3] = f2bs(v[3]);
        *(s16x4*)(dst + elem) = o;
    }
}

__global__ __launch_bounds__(256) void convert_w(
    const float* __restrict__ W, short* __restrict__ dst)
{
    const int stride = gridDim.x * blockDim.x;
    for (int i = blockIdx.x * blockDim.x + threadIdx.x; i < DD * DD / 4; i += stride) {
        f32x4 v = *(const f32x4*)(W + i * 4);
        s16x4 o; o[0] = f2bs(v[0]); o[1] = f2bs(v[1]); o[2] = f2bs(v[2]); o[3] = f2bs(v[3]);
        *(s16x4*)(dst + i * 4) = o;
    }
}

// New: one-shot fp32 -> bf16 conversion of X (4096x1024). Removes the per-
// K-step cvt chain from qkv_gemm2's staging path (X was re-converted 24x,
// once per N-block) and makes the A operand global_load_lds-able.
__global__ __launch_bounds__(256) void convert_x(
    const float* __restrict__ X, short* __restrict__ dst)
{
    const int stride = gridDim.x * blockDim.x;
    for (int i = blockIdx.x * blockDim.x + threadIdx.x; i < MM * DD / 4; i += stride) {
        f32x4 v = *(const f32x4*)(X + i * 4);
        s16x4 o; o[0] = f2bs(v[0]); o[1] = f2bs(v[1]); o[2] = f2bs(v[2]); o[3] = f2bs(v[3]);
        *(s16x4*)(dst + i * 4) = o;
    }
}

// ---------------------------------------------------------------------------
// Fused QKV GEMM. r13: bf16 X input + global_load_lds width-16 staging.
// Wave w stages rows [w*32, w*32+32) of both tiles; lane l covers row
// +(l>>3), 16B chunk (l&7) of the linear LDS dest. Global src chunk is
// (l&7)^(l>>3) so physical slot (r,p) holds logical chunk p^(r&7), matching
// lds_off() on the read side (involution verified).
// ---------------------------------------------------------------------------
__global__ __launch_bounds__(256) void qkv_gemm2(
    const short* __restrict__ Xb, const short* __restrict__ Wcat,
    const float* __restrict__ bq, const float* __restrict__ bk, const float* __restrict__ bv,
    bf16* __restrict__ outQ, bf16* __restrict__ outK, bf16* __restrict__ outV)
{
    __shared__ short As[128 * 64];
    __shared__ short Bs[128 * 64];

    const int tid  = threadIdx.x;
    const int lane = tid & 63;
    const int wave = tid >> 6;
    const int wm   = wave & 1;
    const int wn   = wave >> 1;
    const int g    = lane >> 4;
    const int fr   = lane & 15;

    const int m0 = blockIdx.x * 128;
    const int n0 = blockIdx.y * 128;

    const int srow = wave * 32 + (lane >> 3);
    const int schk = (lane & 7) ^ (lane >> 3);
    const short* agl = Xb   + (size_t)(m0 + srow) * DD + schk * 8;
    const short* bgl = Wcat + (size_t)(n0 + srow) * DD + schk * 8;
    short* alds = &As[wave * 32 * 64];
    short* blds = &Bs[wave * 32 * 64];

    floatx4 acc[4][4];
#pragma unroll
    for (int i = 0; i < 4; ++i)
#pragma unroll
        for (int j = 0; j < 4; ++j) acc[i][j] = (floatx4){0.f, 0.f, 0.f, 0.f};

    for (int kb = 0; kb < DD; kb += 64) {
        __syncthreads();   // prior iteration's LDS reads complete
#pragma unroll
        for (int j = 0; j < 4; ++j) {
            GL16(agl + kb + j * 8 * DD, alds + j * 8 * 64);
            GL16(bgl + kb + j * 8 * DD, blds + j * 8 * 64);
        }
        __syncthreads();   // compiler drains vmcnt before s_barrier

#pragma unroll
        for (int kk = 0; kk < 2; ++kk) {
            const int kc = kk * 4 + g;
            short8 af[4], bf[4];
#pragma unroll
            for (int t = 0; t < 4; ++t) {
                af[t] = *(const short8*)&As[lds_off(wm * 64 + t * 16 + fr, kc)];
                bf[t] = *(const short8*)&Bs[lds_off(wn * 64 + t * 16 + fr, kc)];
            }
#pragma unroll
            for (int mt = 0; mt < 4; ++mt)
#pragma unroll
                for (int nt = 0; nt < 4; ++nt)
                    acc[mt][nt] = __builtin_amdgcn_mfma_f32_16x16x32_bf16(
                        af[mt], bf[nt], acc[mt][nt], 0, 0, 0);
        }
    }

#pragma unroll
    for (int nt = 0; nt < 4; ++nt) {
        const int n  = n0 + wn * 64 + nt * 16 + fr;
        const int z  = n >> 10;
        const int nn = n & 1023;
        const int h_ = nn >> 6;
        const int d_ = nn & 63;
        const float biasv = ((z == 0) ? bq : (z == 1) ? bk : bv)[nn];
        bf16* outp = (z == 0) ? outQ : (z == 1) ? outK : outV;
#pragma unroll
        for (int mt = 0; mt < 4; ++mt) {
#pragma unroll
            for (int reg = 0; reg < 4; ++reg) {
                const int m  = m0 + wm * 64 + mt * 16 + g * 4 + reg;
                const int b_ = m >> 11;
                const int s_ = m & (SS - 1);
                const float v = acc[mt][nt][reg] + biasv;
                size_t off;
                if (z == 2) off = ((size_t)((b_ * HH + h_) * HD + d_)) * SS + s_;  // V^T
                else        off = ((size_t)((b_ * HH + h_) * SS + s_)) * HD + d_;  // Q,K
                outp[off] = __float2bfloat16(v);
            }
        }
    }
}

// ---------------------------------------------------------------------------
// Output projection. r13: same global_load_lds staging as qkv_gemm2.
// ---------------------------------------------------------------------------
__global__ __launch_bounds__(256) void o_gemm2(
    const short* __restrict__ A, const short* __restrict__ Wob,
    const float* __restrict__ bias, float* __restrict__ out)
{
    __shared__ short As[128 * 64];
    __shared__ short Bs[128 * 64];

    const int tid  = threadIdx.x;
    const int lane = tid & 63;
    const int wave = tid >> 6;
    const int wm   = wave & 1;
    const int wn   = wave >> 1;
    const int g    = lane >> 4;
    const int fr   = lane & 15;

    const int m0 = blockIdx.x * 128;
    const int n0 = blockIdx.y * 128;

    const int srow = wave * 32 + (lane >> 3);
    const int schk = (lane & 7) ^ (lane >> 3);
    const short* agl = A   + (size_t)(m0 + srow) * DD + schk * 8;
    const short* bgl = Wob + (size_t)(n0 + srow) * DD + schk * 8;
    short* alds = &As[wave * 32 * 64];
    short* blds = &Bs[wave * 32 * 64];

    floatx4 acc[4][4];
#pragma unroll
    for (int i = 0; i < 4; ++i)
#pragma unroll
        for (int j = 0; j < 4; ++j) acc[i][j] = (floatx4){0.f, 0.f, 0.f, 0.f};

    for (int kb = 0; kb < DD; kb += 64) {
        __syncthreads();
#pragma unroll
        for (int j = 0; j < 4; ++j) {
            GL16(agl + kb + j * 8 * DD, alds + j * 8 * 64);
            GL16(bgl + kb + j * 8 * DD, blds + j * 8 * 64);
        }
        __syncthreads();

#pragma unroll
        for (int kk = 0; kk < 2; ++kk) {
            const int kc = kk * 4 + g;
            short8 af[4], bf[4];
#pragma unroll
            for (int t = 0; t < 4; ++t) {
                af[t] = *(const short8*)&As[lds_off(wm * 64 + t * 16 + fr, kc)];
                bf[t] = *(const short8*)&Bs[lds_off(wn * 64 + t * 16 + fr, kc)];
            }
#pragma unroll
            for (int mt = 0; mt < 4; ++mt)
#pragma unroll
                for (int nt = 0; nt < 4; ++nt)
                    acc[mt][nt] = __builtin_amdgcn_mfma_f32_16x16x32_bf16(
                        af[mt], bf[nt], acc[mt][nt], 0, 0, 0);
        }
    }

#pragma unroll
    for (int nt = 0; nt < 4; ++nt) {
        const int n = n0 + wn * 64 + nt * 16 + fr;
        const float biasv = bias[n];
#pragma unroll
        for (int mt = 0; mt < 4; ++mt) {
#pragma unroll
            for (int reg = 0; reg < 4; ++reg) {
                const int m = m0 + wm * 64 + mt * 16 + g * 4 + reg;
                out[(size_t)m * DD + n] = acc[mt][nt][reg] + biasv;
            }
        }
    }
}

// ---------------------------------------------------------------------------
// MFMA flash attention v5: block-level K/V LDS staging + XCD locality.
// (unchanged this round — qkv_gemm2 is the measured bottleneck)
// ---------------------------------------------------------------------------
__global__ __launch_bounds__(256) void flash_mfma5(
    const bf16* __restrict__ Qh,   // [B,H,S,HD]
    const bf16* __restrict__ Kh,   // [B,H,S,HD]
    const bf16* __restrict__ VT,   // [B,H,HD,S]
    const int*  __restrict__ pad,  // [B,S] int32, nonzero = masked key
    bf16* __restrict__ attn)       // [B,S,D]
{
    __shared__ short Ks[64 * 64];       // 64 keys x 64 dims, swizzled, 8 KB
    __shared__ short Vs[64 * 64];       // 64 dims x 64 keys (V^T), 8 KB
    __shared__ short Pld[4][16 * 64];   // per-wave P tiles, 8 KB

    const int tid  = threadIdx.x;
    const int lane = tid & 63;
    const int wave = tid >> 6;
    const int xcd = blockIdx.x & 7;
    const int idx = blockIdx.x >> 3;        // 0..127
    const int bh  = (xcd << 2) | (idx & 3); // 4 heads per XCD group
    const int qt  = 31 - (idx >> 2);        // 64-row q-tile, longest first
    const int q0  = qt * 64 + wave * 16;
    const int b_  = bh >> 4;
    const int h_  = bh & 15;

    const int g  = lane >> 4;   // 0..3
    const int fr = lane & 15;
    const int k8 = g * 8;

    short* myP = Pld[wave];

    // Q fragments (2 dim-halves), pre-scaled by 1/sqrt(64)=0.125
    const bf16* qbase = Qh + ((size_t)bh * SS + q0 + fr) * HD + k8;
    short8 qf[2];
#pragma unroll
    for (int hh = 0; hh < 2; ++hh) {
        short8 rawq = *(const short8*)((const short*)qbase + hh * 32);
#pragma unroll
        for (int j = 0; j < 8; ++j) qf[hh][j] = f2bs(bs2f(rawq[j]) * 0.125f);
    }

    const int* padrow = pad + b_ * SS;
    const short* kbh = (const short*)(Kh + (size_t)bh * SS * HD);
    const short* vbh = (const short*)(VT + (size_t)bh * HD * SS);

    // staging coords: thread t -> row t>>2 (0..63), chunk pair (t&3)*2
    const int sr = tid >> 2;
    const int cp = (tid & 3) * 2;

    floatx4 o[4] = {{0,0,0,0},{0,0,0,0},{0,0,0,0},{0,0,0,0}};
    float l_acc[4] = {0.f, 0.f, 0.f, 0.f};

    const int kend = qt * 64 + 63;   // uniform across the block
    for (int kb = 0; kb <= kend; kb += 64) {
        __syncthreads();   // previous iteration's LDS reads complete
        // ---- stage K rows kb..kb+63 (dims 0..63) and V^T dims 0..63 ----
        {
            const short* gk = kbh + (size_t)(kb + sr) * HD + cp * 8;
            *(short8*)&Ks[lds_off(sr, cp)]     = *(const short8*)gk;
            *(short8*)&Ks[lds_off(sr, cp + 1)] = *(const short8*)(gk + 8);
            const short* gv = vbh + (size_t)sr * SS + kb + cp * 8;
            *(short8*)&Vs[lds_off(sr, cp)]     = *(const short8*)gv;
            *(short8*)&Vs[lds_off(sr, cp + 1)] = *(const short8*)(gv + 8);
        }
        __syncthreads();

        // ---- QK^T from LDS: 8 MFMAs -> 4 C frags ----
        floatx4 c[4];
#pragma unroll
        for (int t = 0; t < 4; ++t) {
            short8 kf0 = *(const short8*)&Ks[(t * 16 + fr) * 64 + ((g       ^ (fr & 7)) << 3)];
            short8 kf1 = *(const short8*)&Ks[(t * 16 + fr) * 64 + (((g + 4) ^ (fr & 7)) << 3)];
            floatx4 cc = {0, 0, 0, 0};
            cc = __builtin_amdgcn_mfma_f32_16x16x32_bf16(qf[0], kf0, cc, 0, 0, 0);
            cc = __builtin_amdgcn_mfma_f32_16x16x32_bf16(qf[1], kf1, cc, 0, 0, 0);
            c[t] = cc;
        }

        bool pm[4];
#pragma unroll
        for (int t = 0; t < 4; ++t) pm[t] = (padrow[kb + t * 16 + fr] != 0);

        // ---- unnormalized softmax numerators (no max, no rescale) ----
#pragma unroll
        for (int reg = 0; reg < 4; ++reg) {
            const int q   = q0 + g * 4 + reg;
            const int row = g * 4 + reg;
#pragma unroll
            for (int t = 0; t < 4; ++t) {
                const int key = kb + t * 16 + fr;
                const float p = (key <= q && !pm[t]) ? __expf(c[t][reg]) : 0.f;
                l_acc[reg] += p;
                const int col = t * 16 + fr;
                myP[row * 64 + (((col >> 3) ^ (row & 7)) << 3) + (col & 7)] = f2bs(p);
            }
        }

        // ---- P A-frags (same-wave DS ordering) + PV from staged V ----
        short8 pf0 = *(const short8*)&myP[fr * 64 + ((g       ^ (fr & 7)) << 3)];
        short8 pf1 = *(const short8*)&myP[fr * 64 + (((g + 4) ^ (fr & 7)) << 3)];
#pragma unroll
        for (int n = 0; n < 4; ++n) {
            short8 vf0 = *(const short8*)&Vs[(n * 16 + fr) * 64 + ((g       ^ (fr & 7)) << 3)];
            short8 vf1 = *(const short8*)&Vs[(n * 16 + fr) * 64 + (((g + 4) ^ (fr & 7)) << 3)];
            o[n] = __builtin_amdgcn_mfma_f32_16x16x32_bf16(pf0, vf0, o[n], 0, 0, 0);
            o[n] = __builtin_amdgcn_mfma_f32_16x16x32_bf16(pf1, vf1, o[n], 0, 0, 0);
        }
    }

    // ---- epilogue: reduce l across the 16-lane group, once ----
    float inv[4];
#pragma unroll
    for (int reg = 0; reg < 4; ++reg) {
        float l = l_acc[reg];
#pragma unroll
        for (int off = 1; off < 16; off <<= 1) l += __shfl_xor(l, off);
        inv[reg] = 1.f / fmaxf(l, 1e-38f);
    }
#pragma unroll
    for (int n = 0; n < 4; ++n) {
#pragma unroll
        for (int reg = 0; reg < 4; ++reg) {
            const int q = q0 + g * 4 + reg;
            attn[((size_t)(b_ * SS + q)) * DD + h_ * HD + n * 16 + fr] =
                __float2bfloat16(o[n][reg] * inv[reg]);
        }
    }
}

// ---------------------------------------------------------------------------
extern "C" void kernel_launch(void* const* d_in, const int* in_sizes, int n_in,
                              void* d_out, int out_size, void* d_ws, size_t ws_size,
                              hipStream_t stream) {
    const float* x   = (const float*)d_in[0];
    const int*   pad = (const int*)  d_in[1];
    const float* Wq  = (const float*)d_in[2];
    const float* bq  = (const float*)d_in[3];
    const float* Wk  = (const float*)d_in[4];
    const float* bk  = (const float*)d_in[5];
    const float* Wv  = (const float*)d_in[6];
    const float* bv  = (const float*)d_in[7];
    const float* Wo  = (const float*)d_in[8];
    const float* bo  = (const float*)d_in[9];
    float* out = (float*)d_out;                  // fp32 output

    const size_t NELEM = (size_t)BB * HH * SS * HD;  // 4,194,304
    bf16* Qh   = (bf16*)d_ws;
    bf16* Kh   = Qh + NELEM;
    bf16* VT   = Kh + NELEM;
    bf16* attn = VT + NELEM;
    // Scratch in d_out (16.78 MB): Wcat 6.29 MB + Xb 8.39 MB, both consumed
    // before o_gemm2 overwrites d_out with the final fp32 result.
    short* Wcat = (short*)d_out;
    short* Xb   = (short*)d_out + (size_t)NQKV * DD;
    short* Wob  = (short*)Qh;                    // scratch in ws after flash

    convert_wcat<<<768, 256, 0, stream>>>(Wq, Wk, Wv, Wcat);
    convert_x<<<1024, 256, 0, stream>>>(x, Xb);

    dim3 gq(MM / 128, NQKV / 128);
    qkv_gemm2<<<gq, 256, 0, stream>>>(Xb, Wcat, bq, bk, bv, Qh, Kh, VT);

    flash_mfma5<<<BB * HH * 32, 256, 0, stream>>>(Qh, Kh, VT, pad, attn);

    convert_w<<<512, 256, 0, stream>>>(Wo, Wob);

    dim3 go(MM / 128, DD / 128);
    o_gemm2<<<go, 256, 0, stream>>>((const short*)attn, Wob, bo, out);
}